// Round 2
// baseline (731.827 us; speedup 1.0000x reference)
//
#include <hip/hip_runtime.h>
#include <math.h>

typedef unsigned short u16;
typedef unsigned int u32;
typedef __bf16 bf16x8 __attribute__((ext_vector_type(8)));
typedef float f32x4 __attribute__((ext_vector_type(4)));

#define BM 128
#define BN 128
#define BK 32

__device__ __forceinline__ u16 f2b(float f) {
    u32 u = __float_as_uint(f);
    return (u16)((u + 0x7FFFu + ((u >> 16) & 1u)) >> 16);
}
__device__ __forceinline__ float b2f(u16 h) {
    return __uint_as_float(((u32)h) << 16);
}

// async global->LDS, 16B per lane. LDS dest is wave-uniform base + lane*16.
#define GLL16(gp, lp)                                                          \
    __builtin_amdgcn_global_load_lds(                                          \
        (__attribute__((address_space(1))) void*)(const_cast<u16*>(gp)),       \
        (__attribute__((address_space(3))) void*)(lp), 16, 0, 0)

// ---------------------------------------------------------------------------
// NT GEMM: A [M x K] row-major, B [N x K] row-major (B^T input), D [M x N]
// EPI: 0 = +bias -> bf16, 1 = softplus(scale*x) causal-masked -> bf16,
//      2 = plain -> bf16, 3 = +bias -> f32
// EARLY: skip fully-masked (col tile > row tile) blocks, write zeros
// KLIM: truncate K-loop at r0+BM (causal: only s <= t_max contribute)
// ---------------------------------------------------------------------------
template <int EPI, bool EARLY, bool KLIM>
__global__ __launch_bounds__(256) void gemm_nt(
    const u16* __restrict__ A, long long sAz,
    const u16* __restrict__ B, long long sBz,
    void* __restrict__ Dv, long long sDz,
    const float* __restrict__ bias,
    int M, int N, int K, float scale)
{
    const int bx = blockIdx.x, by = blockIdx.y, bz = blockIdx.z;
    const int r0 = by * BM, c0 = bx * BN;

    if (EARLY && c0 >= r0 + BM) {
        // fully masked tile: write zeros (buffer is poisoned, must be cleared)
        u16* Dp = (u16*)Dv + (long long)bz * sDz + (long long)r0 * N + c0;
        uint4 z4; z4.x = z4.y = z4.z = z4.w = 0u;
        #pragma unroll
        for (int j = 0; j < 8; j++) {
            int lin = threadIdx.x + j * 256;   // 2048 chunks of 8 u16
            int rr = lin >> 4, cc = (lin & 15) * 8;
            *(uint4*)(Dp + (long long)rr * N + cc) = z4;
        }
        return;
    }

    __shared__ __align__(16) u16 As[BM * BK];
    __shared__ __align__(16) u16 Bs[BN * BK];

    const int tid = threadIdx.x;
    const int lane = tid & 63, wave = tid >> 6;
    const int wm = (wave >> 1) * 64, wn = (wave & 1) * 64;

    const u16* Ab = A + (long long)bz * sAz + (long long)r0 * K;
    const u16* Bb = B + (long long)bz * sBz + (long long)c0 * K;

    const int ra0 = tid >> 2;          // row 0..63 (second issue: +64)
    const int ca0 = (tid & 3) * 8;     // k-chunk within row

    f32x4 acc[4][4];
    #pragma unroll
    for (int i = 0; i < 4; i++)
        #pragma unroll
        for (int j = 0; j < 4; j++)
            acc[i][j] = (f32x4){0.f, 0.f, 0.f, 0.f};

    const int kEnd = KLIM ? ((r0 + BM) < K ? (r0 + BM) : K) : K;

    for (int k0 = 0; k0 < kEnd; k0 += BK) {
        GLL16(Ab + (long long)ra0 * K + k0 + ca0,        &As[tid * 8]);
        GLL16(Ab + (long long)(ra0 + 64) * K + k0 + ca0, &As[(tid + 256) * 8]);
        GLL16(Bb + (long long)ra0 * K + k0 + ca0,        &Bs[tid * 8]);
        GLL16(Bb + (long long)(ra0 + 64) * K + k0 + ca0, &Bs[(tid + 256) * 8]);
        __syncthreads();   // compiler drains vmcnt(0) before s_barrier

        bf16x8 af[4], bfv[4];
        #pragma unroll
        for (int i = 0; i < 4; i++) {
            af[i]  = *(const bf16x8*)&As[(wm + i * 16 + (lane & 15)) * BK + (lane >> 4) * 8];
            bfv[i] = *(const bf16x8*)&Bs[(wn + i * 16 + (lane & 15)) * BK + (lane >> 4) * 8];
        }
        #pragma unroll
        for (int i = 0; i < 4; i++)
            #pragma unroll
            for (int j = 0; j < 4; j++)
                acc[i][j] = __builtin_amdgcn_mfma_f32_16x16x32_bf16(af[i], bfv[j], acc[i][j], 0, 0, 0);
        __syncthreads();
    }

    // epilogue: C/D layout col=lane&15, row=(lane>>4)*4+reg
    const int rl = (lane >> 4) * 4, cl = lane & 15;
    #pragma unroll
    for (int i = 0; i < 4; i++) {
        #pragma unroll
        for (int j = 0; j < 4; j++) {
            const int gr0 = r0 + wm + i * 16 + rl;
            const int gc  = c0 + wn + j * 16 + cl;
            #pragma unroll
            for (int v = 0; v < 4; v++) {
                const int gr = gr0 + v;
                float val = acc[i][j][v];
                const long long o = (long long)bz * sDz + (long long)gr * N + gc;
                if (EPI == 0) {
                    ((u16*)Dv)[o] = f2b(val + bias[gc]);
                } else if (EPI == 1) {
                    float xs = val * scale;
                    float r = (gc <= gr) ? ((xs > 15.f) ? xs : log1pf(__expf(xs))) : 0.f;
                    ((u16*)Dv)[o] = f2b(r);
                } else if (EPI == 2) {
                    ((u16*)Dv)[o] = f2b(val);
                } else {
                    ((float*)Dv)[o] = val + bias[gc];
                }
            }
        }
    }
}

// ---------------------------------------------------------------------------
// fp32 -> bf16 conversion, vectorized x4
// ---------------------------------------------------------------------------
__global__ void f2b_kern(const float* __restrict__ in, u16* __restrict__ out, int n4) {
    int i = blockIdx.x * blockDim.x + threadIdx.x;
    if (i >= n4) return;
    float4 f = ((const float4*)in)[i];
    uint2 o;
    o.x = (u32)f2b(f.x) | ((u32)f2b(f.y) << 16);
    o.y = (u32)f2b(f.z) | ((u32)f2b(f.w) << 16);
    ((uint2*)out)[i] = o;
}

// ---------------------------------------------------------------------------
// Angle suffix-sum (angle[t] = sum_{s>=t} emb[idx[s]]) in 3 phases.
// ---------------------------------------------------------------------------
#define TT 1024
#define CC2 512
#define NCH 32
#define CL 32

__global__ void angle_partial(const int* __restrict__ idx, const float* __restrict__ emb,
                              float* __restrict__ partial) {
    int b = blockIdx.x >> 5, ch = blockIdx.x & 31;
    int c = threadIdx.x;               // 0..511
    float s = 0.f;
    int tb = ch * CL;
    for (int t = 0; t < CL; t++) {
        int row = idx[b * TT + tb + t];
        s += emb[(long long)row * CC2 + c];
    }
    partial[((long long)b * NCH + ch) * CC2 + c] = s;
}

__global__ void angle_scan(float* __restrict__ partial) {
    int b = blockIdx.x, c = threadIdx.x;
    float run = 0.f;
    for (int ch = NCH - 1; ch >= 0; ch--) {
        long long o = ((long long)b * NCH + ch) * CC2 + c;
        float p = partial[o];
        partial[o] = run;              // exclusive suffix (chunks after this one)
        run += p;
    }
}

__global__ void angle_final(const int* __restrict__ idx, const float* __restrict__ emb,
                            const float* __restrict__ partial,
                            float* __restrict__ angle) {
    int b = blockIdx.x >> 5, ch = blockIdx.x & 31;
    int c = threadIdx.x;
    float run = partial[((long long)b * NCH + ch) * CC2 + c];
    for (int t = CL - 1; t >= 0; t--) {
        int tt = ch * CL + t;
        int row = idx[b * TT + tt];
        run += emb[(long long)row * CC2 + c];
        angle[((long long)b * TT + tt) * CC2 + c] = run;
    }
}

// ---------------------------------------------------------------------------
// in-place pair rotation of k and q: (z0,z1) -> (c*z0 - s*z1, s*z0 + c*z1)
// ---------------------------------------------------------------------------
__global__ void rotate_kq(u16* __restrict__ k, u16* __restrict__ q,
                          const float* __restrict__ angle, int npairs) {
    int i = blockIdx.x * blockDim.x + threadIdx.x;
    if (i >= npairs) return;
    float cs, sn;
    __sincosf(angle[i], &sn, &cs);
    u32 zk = ((u32*)k)[i];
    float k0 = b2f((u16)(zk & 0xffff)), k1 = b2f((u16)(zk >> 16));
    ((u32*)k)[i] = (u32)f2b(cs * k0 - sn * k1) | ((u32)f2b(sn * k0 + cs * k1) << 16);
    u32 zq = ((u32*)q)[i];
    float q0 = b2f((u16)(zq & 0xffff)), q1 = b2f((u16)(zq >> 16));
    ((u32*)q)[i] = (u32)f2b(cs * q0 - sn * q1) | ((u32)f2b(sn * q0 + cs * q1) << 16);
}

// inverse rotation: (z0,z1) -> (c*z0 + s*z1, -s*z0 + c*z1)
__global__ void invrot_kern(const u16* __restrict__ a, u16* __restrict__ y,
                            const float* __restrict__ angle, int npairs) {
    int i = blockIdx.x * blockDim.x + threadIdx.x;
    if (i >= npairs) return;
    float cs, sn;
    __sincosf(angle[i], &sn, &cs);
    u32 z = ((const u32*)a)[i];
    float z0 = b2f((u16)(z & 0xffff)), z1 = b2f((u16)(z >> 16));
    ((u32*)y)[i] = (u32)f2b(cs * z0 + sn * z1) | ((u32)f2b(-sn * z0 + cs * z1) << 16);
}

// ---------------------------------------------------------------------------
// rotate v and transpose to vT[b][c][t]  (so wei@v becomes an NT GEMM)
// tile: 64 t x 32 c2 (=64 c); LDS transpose with +2 padding
// ---------------------------------------------------------------------------
__global__ void rot_transpose_v(const u16* __restrict__ v,
                                const float* __restrict__ angle,
                                u16* __restrict__ vT) {
    __shared__ u16 lds[64][66];        // [c_local][t_local]
    int b = blockIdx.z;
    int t0 = blockIdx.y * 64;
    int c20 = blockIdx.x * 32;
    int tid = threadIdx.x;

    #pragma unroll
    for (int j = 0; j < 8; j++) {
        int p = tid + j * 256;         // 0..2047
        int tl = p >> 5, c2l = p & 31;
        long long src = ((long long)(b * TT + t0 + tl)) * CC2 + c20 + c2l;
        u32 z = ((const u32*)v)[src];
        float z0 = b2f((u16)(z & 0xffff)), z1 = b2f((u16)(z >> 16));
        float cs, sn;
        __sincosf(angle[src], &sn, &cs);
        lds[2 * c2l][tl]     = f2b(cs * z0 - sn * z1);
        lds[2 * c2l + 1][tl] = f2b(sn * z0 + cs * z1);
    }
    __syncthreads();

    int clc = tid >> 2, tq = (tid & 3) * 16;
    long long dst = ((long long)b * 1024 + (c20 * 2 + clc)) * 1024 + t0 + tq;
    u16 tmp[16];
    #pragma unroll
    for (int j = 0; j < 16; j++) tmp[j] = lds[clc][tq + j];
    u32 w[8];
    #pragma unroll
    for (int j = 0; j < 8; j++) w[j] = (u32)tmp[2 * j] | ((u32)tmp[2 * j + 1] << 16);
    uint4 u0, u1;
    u0.x = w[0]; u0.y = w[1]; u0.z = w[2]; u0.w = w[3];
    u1.x = w[4]; u1.y = w[5]; u1.z = w[6]; u1.w = w[7];
    *(uint4*)(vT + dst) = u0;
    *(uint4*)(vT + dst + 8) = u1;
}

// ---------------------------------------------------------------------------
extern "C" void kernel_launch(void* const* d_in, const int* in_sizes, int n_in,
                              void* d_out, int out_size, void* d_ws, size_t ws_size,
                              hipStream_t stream) {
    const int Bn = 16, T = 1024, C = 1024, C2 = 512;
    const long long TC = (long long)T * C;
    const size_t nx = (size_t)Bn * T * C;          // 16,777,216
    const size_t npairs = (size_t)Bn * T * C2;     // 8,388,608

    const float* x   = (const float*)d_in[0];
    const int*   idx = (const int*)d_in[1];
    const float* Wk  = (const float*)d_in[2];
    const float* bk  = (const float*)d_in[3];
    const float* Wq  = (const float*)d_in[4];
    const float* bq  = (const float*)d_in[5];
    const float* Wv  = (const float*)d_in[6];
    const float* bv  = (const float*)d_in[7];
    const float* Wp  = (const float*)d_in[8];
    const float* bp  = (const float*)d_in[9];
    const float* emb = (const float*)d_in[10];
    float* out = (float*)d_out;

    // workspace layout (~177 MB): 4 bf16 [B*T*C] bufs + angle f32 + weights + partial
    u16* xb  = (u16*)d_ws;          // x bf16; aliased as vT after projections
    u16* kb  = xb + nx;             // k (rotated in place); attn output after GEMM-S
    u16* qb  = kb + nx;             // q (rotated in place); y after invrot
    u16* vb  = qb + nx;             // v; aliased as wei after rot_transpose_v
    float* angle = (float*)(vb + nx);              // [B][T][C2] f32
    u16* Wkb = (u16*)(angle + npairs);
    u16* Wqb = Wkb + (size_t)C * C;
    u16* Wvb = Wqb + (size_t)C * C;
    u16* Wpb = Wvb + (size_t)C * C;
    float* partial = (float*)(Wpb + (size_t)C * C);  // [B][32][512]
    u16* vT  = xb;                  // alias (x dead after projections)
    u16* wei = vb;                  // alias (v dead after rot_transpose_v)

    // 1) conversions to bf16
    f2b_kern<<<(int)(nx / 4 / 256), 256, 0, stream>>>(x, xb, (int)(nx / 4));
    f2b_kern<<<C * C / 4 / 256, 256, 0, stream>>>(Wk, Wkb, C * C / 4);
    f2b_kern<<<C * C / 4 / 256, 256, 0, stream>>>(Wq, Wqb, C * C / 4);
    f2b_kern<<<C * C / 4 / 256, 256, 0, stream>>>(Wv, Wvb, C * C / 4);
    f2b_kern<<<C * C / 4 / 256, 256, 0, stream>>>(Wp, Wpb, C * C / 4);

    // 2) angle suffix-sum
    angle_partial<<<Bn * NCH, 512, 0, stream>>>(idx, emb, partial);
    angle_scan<<<Bn, 512, 0, stream>>>(partial);
    angle_final<<<Bn * NCH, 512, 0, stream>>>(idx, emb, partial, angle);

    // 3) projections (M=16384, N=1024, K=1024), bias fused, bf16 out
    dim3 gP(8, 128, 1);
    gemm_nt<0, false, false><<<gP, 256, 0, stream>>>(xb, 0, Wkb, 0, kb, 0, bk, Bn * T, C, C, 1.f);
    gemm_nt<0, false, false><<<gP, 256, 0, stream>>>(xb, 0, Wqb, 0, qb, 0, bq, Bn * T, C, C, 1.f);
    gemm_nt<0, false, false><<<gP, 256, 0, stream>>>(xb, 0, Wvb, 0, vb, 0, bv, Bn * T, C, C, 1.f);

    // 4) rotations (x dead from here; vT aliases xb)
    rotate_kq<<<(int)(npairs / 256), 256, 0, stream>>>(kb, qb, angle, (int)npairs);
    rot_transpose_v<<<dim3(C2 / 32, T / 64, Bn), 256, 0, stream>>>(vb, angle, vT);

    // 5) wei = softplus(k @ q^T / 32), causal-masked (v dead; wei aliases vb)
    dim3 gS(8, 8, 16);
    gemm_nt<1, true, false><<<gS, 256, 0, stream>>>(kb, TC, qb, TC, wei, (long long)T * T,
                                                    nullptr, T, T, C, 0.03125f);

    // 6) attn = wei @ v  (vT is [N=c][K=s]); K-loop truncated at causal boundary
    gemm_nt<2, false, true><<<gS, 256, 0, stream>>>(wei, (long long)T * T, vT, (long long)C * T,
                                                    kb, TC, nullptr, T, C, T, 1.f);

    // 7) inverse rotation: attn (kb) -> y (qb)
    invrot_kern<<<(int)(npairs / 256), 256, 0, stream>>>(kb, qb, angle, (int)npairs);

    // 8) final projection -> f32 out
    gemm_nt<3, false, false><<<gP, 256, 0, stream>>>(qb, 0, Wpb, 0, out, 0, bp, Bn * T, C, C, 1.f);
}

// Round 3
// 565.778 us; speedup vs baseline: 1.2935x; 1.2935x over previous
//
#include <hip/hip_runtime.h>
#include <math.h>

typedef unsigned short u16;
typedef unsigned int u32;
typedef __bf16 bf16x8 __attribute__((ext_vector_type(8)));
typedef float f32x4 __attribute__((ext_vector_type(4)));

#define BM 128
#define BN 128
#define BK 32

__device__ __forceinline__ u16 f2b(float f) {
    u32 u = __float_as_uint(f);
    return (u16)((u + 0x7FFFu + ((u >> 16) & 1u)) >> 16);
}
__device__ __forceinline__ float b2f(u16 h) {
    return __uint_as_float(((u32)h) << 16);
}

// async global->LDS, 16B per lane. LDS dest is wave-uniform base + lane*16.
#define GLL16(gp, lp)                                                          \
    __builtin_amdgcn_global_load_lds(                                          \
        (__attribute__((address_space(1))) void*)(const_cast<u16*>(gp)),       \
        (__attribute__((address_space(3))) void*)(lp), 16, 0, 0)

// ---------------------------------------------------------------------------
// NT GEMM: A [M x K] row-major, B [N x K] row-major (B^T input), D [M x N]
// EPI: 0 = +bias -> bf16, 1 = softplus(scale*x) causal-masked -> bf16,
//      2 = plain -> bf16, 3 = +bias -> f32
// EARLY: skip fully-masked (col tile > row tile) blocks (no write; that
//        region is provably never staged by the downstream KLIM GEMM)
// KLIM:  truncate K-loop at r0+BM (causal: only s <= t_max contribute)
// SWZ:   XCD-aware block swizzle from 1-D grid. consecutive blocks go to
//        XCDs round-robin (n%8), so we put a data-sharing GROUP at fixed n%8.
//        SWZ=0: group = by (row tile), bx = within, bz = 0.   WB = #bx tiles
//        SWZ=1: group = bz (batch),    w  = within, bx=w&7, by=w>>3. WB = 64
// SPLIT: column tiles 0..7 -> D0, 8..15 -> D1, 16..23 -> D2 (fused QKV),
//        output leading dim 1024, bias selected per tile group.
// ---------------------------------------------------------------------------
template <int EPI, bool EARLY, bool KLIM, int SWZ, bool SPLIT>
__global__ __launch_bounds__(256) void gemm_nt(
    const u16* __restrict__ A, long long sAz,
    const u16* __restrict__ B, long long sBz,
    void* __restrict__ D0, void* __restrict__ D1, void* __restrict__ D2,
    long long sDz,
    const float* __restrict__ bias0, const float* __restrict__ bias1,
    const float* __restrict__ bias2,
    int M, int N, int K, float scale, int WB)
{
    int bx, by, bz;
    {
        const int n = blockIdx.x;
        const int xcd = n & 7, m = n >> 3;
        if (SWZ == 0) {
            by = xcd + 8 * (m / WB);
            bx = m % WB;
            bz = 0;
        } else {
            bz = xcd + 8 * (m / WB);
            const int w = m % WB;
            bx = w & 7;
            by = w >> 3;
        }
    }
    const int r0 = by * BM, c0 = bx * BN;

    if (EARLY && c0 >= r0 + BM) return;   // fully masked tile; never read later

    __shared__ __align__(16) u16 As[BM * BK];
    __shared__ __align__(16) u16 Bs[BN * BK];

    const int tid = threadIdx.x;
    const int lane = tid & 63, wave = tid >> 6;
    const int wm = (wave >> 1) * 64, wn = (wave & 1) * 64;

    const u16* Ab = A + (long long)bz * sAz + (long long)r0 * K;
    const u16* Bb = B + (long long)bz * sBz + (long long)c0 * K;

    const int ra0 = tid >> 2;          // row 0..63 (second issue: +64)
    const int ca0 = (tid & 3) * 8;     // k-chunk within row

    f32x4 acc[4][4];
    #pragma unroll
    for (int i = 0; i < 4; i++)
        #pragma unroll
        for (int j = 0; j < 4; j++)
            acc[i][j] = (f32x4){0.f, 0.f, 0.f, 0.f};

    const int kEnd = KLIM ? ((r0 + BM) < K ? (r0 + BM) : K) : K;

    for (int k0 = 0; k0 < kEnd; k0 += BK) {
        GLL16(Ab + (long long)ra0 * K + k0 + ca0,        &As[tid * 8]);
        GLL16(Ab + (long long)(ra0 + 64) * K + k0 + ca0, &As[(tid + 256) * 8]);
        GLL16(Bb + (long long)ra0 * K + k0 + ca0,        &Bs[tid * 8]);
        GLL16(Bb + (long long)(ra0 + 64) * K + k0 + ca0, &Bs[(tid + 256) * 8]);
        __syncthreads();

        bf16x8 af[4], bfv[4];
        #pragma unroll
        for (int i = 0; i < 4; i++) {
            af[i]  = *(const bf16x8*)&As[(wm + i * 16 + (lane & 15)) * BK + (lane >> 4) * 8];
            bfv[i] = *(const bf16x8*)&Bs[(wn + i * 16 + (lane & 15)) * BK + (lane >> 4) * 8];
        }
        #pragma unroll
        for (int i = 0; i < 4; i++)
            #pragma unroll
            for (int j = 0; j < 4; j++)
                acc[i][j] = __builtin_amdgcn_mfma_f32_16x16x32_bf16(af[i], bfv[j], acc[i][j], 0, 0, 0);
        __syncthreads();
    }

    // output routing (uniform per block)
    void* Dp = D0;
    const float* bp_ = bias0;
    int ldD = N, cbase = c0;
    if (SPLIT) {
        const int sel = bx >> 3;       // 8 tiles per 1024-col group
        Dp  = (sel == 0) ? D0 : (sel == 1) ? D1 : D2;
        bp_ = (sel == 0) ? bias0 : (sel == 1) ? bias1 : bias2;
        ldD = 1024;
        cbase = c0 & 1023;
    }

    // epilogue: C/D layout col=lane&15, row=(lane>>4)*4+reg
    const int rl = (lane >> 4) * 4, cl = lane & 15;
    #pragma unroll
    for (int i = 0; i < 4; i++) {
        #pragma unroll
        for (int j = 0; j < 4; j++) {
            const int gr0 = r0 + wm + i * 16 + rl;
            const int gc  = wn + j * 16 + cl;          // col within tile span
            const int gcd = cbase + gc;                // col in D
            const int gcm = c0 + gc;                   // col for causal mask
            #pragma unroll
            for (int v = 0; v < 4; v++) {
                const int gr = gr0 + v;
                float val = acc[i][j][v];
                const long long o = (long long)bz * sDz + (long long)gr * ldD + gcd;
                if (EPI == 0) {
                    ((u16*)Dp)[o] = f2b(val + bp_[gcd]);
                } else if (EPI == 1) {
                    float xs = val * scale;
                    float r = (gcm <= gr) ? ((xs > 15.f) ? xs : log1pf(__expf(xs))) : 0.f;
                    ((u16*)Dp)[o] = f2b(r);
                } else if (EPI == 2) {
                    ((u16*)Dp)[o] = f2b(val);
                } else {
                    ((float*)Dp)[o] = val + bp_[gcd];
                }
            }
        }
    }
}

// ---------------------------------------------------------------------------
// fp32 -> bf16 conversion, vectorized x4
// ---------------------------------------------------------------------------
__global__ void f2b_kern(const float* __restrict__ in, u16* __restrict__ out, int n4) {
    int i = blockIdx.x * blockDim.x + threadIdx.x;
    if (i >= n4) return;
    float4 f = ((const float4*)in)[i];
    uint2 o;
    o.x = (u32)f2b(f.x) | ((u32)f2b(f.y) << 16);
    o.y = (u32)f2b(f.z) | ((u32)f2b(f.w) << 16);
    ((uint2*)out)[i] = o;
}

// ---------------------------------------------------------------------------
// Angle suffix-sum (angle[t] = sum_{s>=t} emb[idx[s]]) in 3 phases.
// ---------------------------------------------------------------------------
#define TT 1024
#define CC2 512
#define NCH 32
#define CL 32

__global__ void angle_partial(const int* __restrict__ idx, const float* __restrict__ emb,
                              float* __restrict__ partial) {
    int b = blockIdx.x >> 5, ch = blockIdx.x & 31;
    int c = threadIdx.x;               // 0..511
    float s = 0.f;
    int tb = ch * CL;
    for (int t = 0; t < CL; t++) {
        int row = idx[b * TT + tb + t];
        s += emb[(long long)row * CC2 + c];
    }
    partial[((long long)b * NCH + ch) * CC2 + c] = s;
}

__global__ void angle_scan(float* __restrict__ partial) {
    int b = blockIdx.x, c = threadIdx.x;
    float run = 0.f;
    for (int ch = NCH - 1; ch >= 0; ch--) {
        long long o = ((long long)b * NCH + ch) * CC2 + c;
        float p = partial[o];
        partial[o] = run;              // exclusive suffix (chunks after this one)
        run += p;
    }
}

__global__ void angle_final(const int* __restrict__ idx, const float* __restrict__ emb,
                            const float* __restrict__ partial,
                            float* __restrict__ angle) {
    int b = blockIdx.x >> 5, ch = blockIdx.x & 31;
    int c = threadIdx.x;
    float run = partial[((long long)b * NCH + ch) * CC2 + c];
    for (int t = CL - 1; t >= 0; t--) {
        int tt = ch * CL + t;
        int row = idx[b * TT + tt];
        run += emb[(long long)row * CC2 + c];
        angle[((long long)b * TT + tt) * CC2 + c] = run;
    }
}

// ---------------------------------------------------------------------------
// in-place pair rotation of k and q: (z0,z1) -> (c*z0 - s*z1, s*z0 + c*z1)
// ---------------------------------------------------------------------------
__global__ void rotate_kq(u16* __restrict__ k, u16* __restrict__ q,
                          const float* __restrict__ angle, int npairs) {
    int i = blockIdx.x * blockDim.x + threadIdx.x;
    if (i >= npairs) return;
    float cs, sn;
    __sincosf(angle[i], &sn, &cs);
    u32 zk = ((u32*)k)[i];
    float k0 = b2f((u16)(zk & 0xffff)), k1 = b2f((u16)(zk >> 16));
    ((u32*)k)[i] = (u32)f2b(cs * k0 - sn * k1) | ((u32)f2b(sn * k0 + cs * k1) << 16);
    u32 zq = ((u32*)q)[i];
    float q0 = b2f((u16)(zq & 0xffff)), q1 = b2f((u16)(zq >> 16));
    ((u32*)q)[i] = (u32)f2b(cs * q0 - sn * q1) | ((u32)f2b(sn * q0 + cs * q1) << 16);
}

// inverse rotation: (z0,z1) -> (c*z0 + s*z1, -s*z0 + c*z1)
__global__ void invrot_kern(const u16* __restrict__ a, u16* __restrict__ y,
                            const float* __restrict__ angle, int npairs) {
    int i = blockIdx.x * blockDim.x + threadIdx.x;
    if (i >= npairs) return;
    float cs, sn;
    __sincosf(angle[i], &sn, &cs);
    u32 z = ((const u32*)a)[i];
    float z0 = b2f((u16)(z & 0xffff)), z1 = b2f((u16)(z >> 16));
    ((u32*)y)[i] = (u32)f2b(cs * z0 + sn * z1) | ((u32)f2b(-sn * z0 + cs * z1) << 16);
}

// ---------------------------------------------------------------------------
// rotate v and transpose to vT[b][c][t]  (so wei@v becomes an NT GEMM)
// ---------------------------------------------------------------------------
__global__ void rot_transpose_v(const u16* __restrict__ v,
                                const float* __restrict__ angle,
                                u16* __restrict__ vT) {
    __shared__ u16 lds[64][66];        // [c_local][t_local]
    int b = blockIdx.z;
    int t0 = blockIdx.y * 64;
    int c20 = blockIdx.x * 32;
    int tid = threadIdx.x;

    #pragma unroll
    for (int j = 0; j < 8; j++) {
        int p = tid + j * 256;         // 0..2047
        int tl = p >> 5, c2l = p & 31;
        long long src = ((long long)(b * TT + t0 + tl)) * CC2 + c20 + c2l;
        u32 z = ((const u32*)v)[src];
        float z0 = b2f((u16)(z & 0xffff)), z1 = b2f((u16)(z >> 16));
        float cs, sn;
        __sincosf(angle[src], &sn, &cs);
        lds[2 * c2l][tl]     = f2b(cs * z0 - sn * z1);
        lds[2 * c2l + 1][tl] = f2b(sn * z0 + cs * z1);
    }
    __syncthreads();

    int clc = tid >> 2, tq = (tid & 3) * 16;
    long long dst = ((long long)b * 1024 + (c20 * 2 + clc)) * 1024 + t0 + tq;
    u16 tmp[16];
    #pragma unroll
    for (int j = 0; j < 16; j++) tmp[j] = lds[clc][tq + j];
    u32 w[8];
    #pragma unroll
    for (int j = 0; j < 8; j++) w[j] = (u32)tmp[2 * j] | ((u32)tmp[2 * j + 1] << 16);
    uint4 u0, u1;
    u0.x = w[0]; u0.y = w[1]; u0.z = w[2]; u0.w = w[3];
    u1.x = w[4]; u1.y = w[5]; u1.z = w[6]; u1.w = w[7];
    *(uint4*)(vT + dst) = u0;
    *(uint4*)(vT + dst + 8) = u1;
}

// ---------------------------------------------------------------------------
extern "C" void kernel_launch(void* const* d_in, const int* in_sizes, int n_in,
                              void* d_out, int out_size, void* d_ws, size_t ws_size,
                              hipStream_t stream) {
    const int Bn = 16, T = 1024, C = 1024, C2 = 512;
    const long long TC = (long long)T * C;
    const size_t nx = (size_t)Bn * T * C;          // 16,777,216
    const size_t npairs = (size_t)Bn * T * C2;     // 8,388,608

    const float* x   = (const float*)d_in[0];
    const int*   idx = (const int*)d_in[1];
    const float* Wk  = (const float*)d_in[2];
    const float* bk  = (const float*)d_in[3];
    const float* Wq  = (const float*)d_in[4];
    const float* bq  = (const float*)d_in[5];
    const float* Wv  = (const float*)d_in[6];
    const float* bv  = (const float*)d_in[7];
    const float* Wp  = (const float*)d_in[8];
    const float* bp  = (const float*)d_in[9];
    const float* emb = (const float*)d_in[10];
    float* out = (float*)d_out;

    // workspace (~177 MB): 4 bf16 [B*T*C] + angle f32 + Wall(3C*C) + Wp + partial
    u16* xb  = (u16*)d_ws;          // x bf16; aliased as vT after projections
    u16* kb  = xb + nx;             // k (rotated in place); attn out after GEMM-O
    u16* qb  = kb + nx;             // q (rotated in place); y after invrot
    u16* vb  = qb + nx;             // v; aliased as wei after rot_transpose_v
    float* angle = (float*)(vb + nx);              // [B][T][C2] f32
    u16* Wall = (u16*)(angle + npairs);            // [3072][1024] = Wk|Wq|Wv
    u16* Wpb  = Wall + (size_t)3 * C * C;
    float* partial = (float*)(Wpb + (size_t)C * C);  // [B][32][512]
    u16* vT  = xb;                  // alias (x dead after projections)
    u16* wei = vb;                  // alias (v dead after rot_transpose_v)

    // 1) conversions to bf16 (weights concatenated into Wall)
    f2b_kern<<<(int)(nx / 4 / 256), 256, 0, stream>>>(x, xb, (int)(nx / 4));
    f2b_kern<<<C * C / 4 / 256, 256, 0, stream>>>(Wk, Wall,                       C * C / 4);
    f2b_kern<<<C * C / 4 / 256, 256, 0, stream>>>(Wq, Wall + (size_t)C * C,       C * C / 4);
    f2b_kern<<<C * C / 4 / 256, 256, 0, stream>>>(Wv, Wall + (size_t)2 * C * C,   C * C / 4);
    f2b_kern<<<C * C / 4 / 256, 256, 0, stream>>>(Wp, Wpb, C * C / 4);

    // 2) angle suffix-sum
    angle_partial<<<Bn * NCH, 512, 0, stream>>>(idx, emb, partial);
    angle_scan<<<Bn, 512, 0, stream>>>(partial);
    angle_final<<<Bn * NCH, 512, 0, stream>>>(idx, emb, partial, angle);

    // 3) fused QKV projection: M=16384, N=3072, K=1024; split output k/q/v
    //    3072 blocks, XCD-swizzled by row tile (WB=24)
    gemm_nt<0, false, false, 0, true><<<3072, 256, 0, stream>>>(
        xb, 0, Wall, 0, kb, qb, vb, 0, bk, bq, bv, Bn * T, 3 * C, C, 1.f, 24);

    // 4) rotations (x dead from here; vT aliases xb)
    rotate_kq<<<(int)(npairs / 256), 256, 0, stream>>>(kb, qb, angle, (int)npairs);
    rot_transpose_v<<<dim3(C2 / 32, T / 64, Bn), 256, 0, stream>>>(vb, angle, vT);

    // 5) wei = softplus(k @ q^T / 32), causal-masked; batch-grouped swizzle
    gemm_nt<1, true, false, 1, false><<<1024, 256, 0, stream>>>(
        kb, TC, qb, TC, wei, nullptr, nullptr, (long long)T * T,
        nullptr, nullptr, nullptr, T, T, C, 0.03125f, 64);

    // 6) attn = wei @ v  (vT is [N=c][K=s]); K truncated at causal boundary
    gemm_nt<2, false, true, 1, false><<<1024, 256, 0, stream>>>(
        wei, (long long)T * T, vT, (long long)C * T, kb, nullptr, nullptr, TC,
        nullptr, nullptr, nullptr, T, C, T, 1.f, 64);

    // 7) inverse rotation: attn (kb) -> y (qb)
    invrot_kern<<<(int)(npairs / 256), 256, 0, stream>>>(kb, qb, angle, (int)npairs);

    // 8) final projection -> f32 out; row-tile swizzle (WB=8)
    gemm_nt<3, false, false, 0, false><<<1024, 256, 0, stream>>>(
        qb, 0, Wpb, 0, out, nullptr, nullptr, 0, bp, nullptr, nullptr,
        Bn * T, C, C, 1.f, 8);
}

// Round 4
// 535.560 us; speedup vs baseline: 1.3665x; 1.0564x over previous
//
#include <hip/hip_runtime.h>
#include <math.h>

typedef unsigned short u16;
typedef unsigned int u32;
typedef __bf16 bf16x8 __attribute__((ext_vector_type(8)));
typedef float f32x4 __attribute__((ext_vector_type(4)));

#define BM 128
#define BN 128
#define BK 32

__device__ __forceinline__ u16 f2b(float f) {
    u32 u = __float_as_uint(f);
    return (u16)((u + 0x7FFFu + ((u >> 16) & 1u)) >> 16);
}
__device__ __forceinline__ float b2f(u16 h) {
    return __uint_as_float(((u32)h) << 16);
}

// async global->LDS, 16B per lane. LDS dest is wave-uniform base + lane*16.
#define GLL16(gp, lp)                                                          \
    __builtin_amdgcn_global_load_lds(                                          \
        (__attribute__((address_space(1))) void*)(const_cast<u16*>(gp)),       \
        (__attribute__((address_space(3))) void*)(lp), 16, 0, 0)

// ---------------------------------------------------------------------------
// NT GEMM: A [M x K] row-major, B [N x K] row-major (B^T input), D [M x N]
// EPI: 0 = +bias, pair-rotate, -> bf16 (QKV; v-group stores transposed to D2)
//      1 = softplus(scale*x) causal-masked -> bf16
//      2 = inverse pair-rotate -> bf16
//      3 = +bias -> f32
// EARLY: skip fully-masked (col tile > row tile) blocks (region never read:
//        downstream KLIM GEMM truncates K at exactly this boundary)
// KLIM:  truncate K-loop at r0+BM (causal: only s <= t_max contribute)
// SWZ:   XCD-aware block swizzle from 1-D grid (consecutive blocks -> XCDs
//        round-robin, so a data-sharing GROUP sits at fixed n%8).
//        SWZ=0: group = by (row tile), bx = within, bz = 0.   WB = #bx tiles
//        SWZ=1: group = bz (batch),    w  = within, bx=w&7, by=w>>3. WB = 64
// SPLIT: column tiles 0..7 -> D0 (k), 8..15 -> D1 (q), 16..23 -> D2 (vT).
// cossin: packed per-pair {lo: cos bf16, hi: sin bf16}, row index = global
//         row for EPI=0 (M spans b,t), (bz*1024+row) for EPI=2.
// ---------------------------------------------------------------------------
template <int EPI, bool EARLY, bool KLIM, int SWZ, bool SPLIT>
__global__ __launch_bounds__(256) void gemm_nt(
    const u16* __restrict__ A, long long sAz,
    const u16* __restrict__ B, long long sBz,
    void* __restrict__ D0, void* __restrict__ D1, void* __restrict__ D2,
    long long sDz,
    const float* __restrict__ bias0, const float* __restrict__ bias1,
    const float* __restrict__ bias2,
    const u32* __restrict__ cossin,
    int M, int N, int K, float scale, int WB)
{
    int bx, by, bz;
    {
        const int n = blockIdx.x;
        const int xcd = n & 7, m = n >> 3;
        if (SWZ == 0) {
            by = xcd + 8 * (m / WB);
            bx = m % WB;
            bz = 0;
        } else {
            bz = xcd + 8 * (m / WB);
            const int w = m % WB;
            bx = w & 7;
            by = w >> 3;
        }
    }
    const int r0 = by * BM, c0 = bx * BN;

    if (EARLY && c0 >= r0 + BM) return;   // fully masked tile; never read later

    __shared__ __align__(16) u16 As[BM * BK];
    __shared__ __align__(16) u16 Bs[BN * BK];

    const int tid = threadIdx.x;
    const int lane = tid & 63, wave = tid >> 6;
    const int wm = (wave >> 1) * 64, wn = (wave & 1) * 64;

    const u16* Ab = A + (long long)bz * sAz + (long long)r0 * K;
    const u16* Bb = B + (long long)bz * sBz + (long long)c0 * K;

    const int ra0 = tid >> 2;          // row 0..63 (second issue: +64)
    const int ca0 = (tid & 3) * 8;     // k-chunk within row

    f32x4 acc[4][4];
    #pragma unroll
    for (int i = 0; i < 4; i++)
        #pragma unroll
        for (int j = 0; j < 4; j++)
            acc[i][j] = (f32x4){0.f, 0.f, 0.f, 0.f};

    const int kEnd = KLIM ? ((r0 + BM) < K ? (r0 + BM) : K) : K;

    for (int k0 = 0; k0 < kEnd; k0 += BK) {
        GLL16(Ab + (long long)ra0 * K + k0 + ca0,        &As[tid * 8]);
        GLL16(Ab + (long long)(ra0 + 64) * K + k0 + ca0, &As[(tid + 256) * 8]);
        GLL16(Bb + (long long)ra0 * K + k0 + ca0,        &Bs[tid * 8]);
        GLL16(Bb + (long long)(ra0 + 64) * K + k0 + ca0, &Bs[(tid + 256) * 8]);
        __syncthreads();

        bf16x8 af[4], bfv[4];
        #pragma unroll
        for (int i = 0; i < 4; i++) {
            af[i]  = *(const bf16x8*)&As[(wm + i * 16 + (lane & 15)) * BK + (lane >> 4) * 8];
            bfv[i] = *(const bf16x8*)&Bs[(wn + i * 16 + (lane & 15)) * BK + (lane >> 4) * 8];
        }
        #pragma unroll
        for (int i = 0; i < 4; i++)
            #pragma unroll
            for (int j = 0; j < 4; j++)
                acc[i][j] = __builtin_amdgcn_mfma_f32_16x16x32_bf16(af[i], bfv[j], acc[i][j], 0, 0, 0);
        __syncthreads();
    }

    // output routing (uniform per block)
    void* Dp = D0;
    const float* bp_ = bias0;
    int ldD = N, cbase = c0, sel = 0;
    if (SPLIT) {
        sel = bx >> 3;                 // 8 tiles per 1024-col group
        Dp  = (sel == 0) ? D0 : (sel == 1) ? D1 : D2;
        bp_ = (sel == 0) ? bias0 : (sel == 1) ? bias1 : bias2;
        ldD = 1024;
        cbase = c0 & 1023;
    }

    // epilogue: C/D layout col=lane&15, row=(lane>>4)*4+reg
    const int rl = (lane >> 4) * 4, cl = lane & 15;

    if (EPI == 0 && sel == 2) {
        // v group: bias + rotate + TRANSPOSED store into vT[b][c][t]
        #pragma unroll
        for (int i = 0; i < 4; i++) {
            #pragma unroll
            for (int j = 0; j < 4; j++) {
                const int gr0 = r0 + wm + i * 16 + rl;       // 4-aligned t base
                const int gcd = cbase + wn + j * 16 + cl;    // v column
                u16 pk[4];
                #pragma unroll
                for (int v = 0; v < 4; v++) {
                    const int gr = gr0 + v;
                    float my = acc[i][j][v] + bp_[gcd];
                    float other = __shfl_xor(my, 1);
                    u32 csn = cossin[(long long)gr * 512 + (gcd >> 1)];
                    float cs = b2f((u16)(csn & 0xffff)), sn = b2f((u16)(csn >> 16));
                    float res = (gcd & 1) ? (sn * other + cs * my)
                                          : (cs * my - sn * other);
                    pk[v] = f2b(res);
                }
                const int bb = gr0 >> 10, tt = gr0 & 1023;
                u16* dst = (u16*)Dp + ((((long long)bb << 10) + gcd) << 10) + tt;
                uint2 pw;
                pw.x = (u32)pk[0] | ((u32)pk[1] << 16);
                pw.y = (u32)pk[2] | ((u32)pk[3] << 16);
                *(uint2*)dst = pw;
            }
        }
        return;
    }

    #pragma unroll
    for (int i = 0; i < 4; i++) {
        #pragma unroll
        for (int j = 0; j < 4; j++) {
            const int gr0 = r0 + wm + i * 16 + rl;
            const int gc  = wn + j * 16 + cl;          // col within tile span
            const int gcd = cbase + gc;                // col in D
            const int gcm = c0 + gc;                   // col for causal mask
            #pragma unroll
            for (int v = 0; v < 4; v++) {
                const int gr = gr0 + v;
                float val = acc[i][j][v];
                const long long o = (long long)bz * sDz + (long long)gr * ldD + gcd;
                if (EPI == 0) {
                    float my = val + bp_[gcd];
                    float other = __shfl_xor(my, 1);
                    u32 csn = cossin[(long long)gr * 512 + (gcd >> 1)];
                    float cs = b2f((u16)(csn & 0xffff)), sn = b2f((u16)(csn >> 16));
                    float res = (gcd & 1) ? (sn * other + cs * my)
                                          : (cs * my - sn * other);
                    ((u16*)Dp)[o] = f2b(res);
                } else if (EPI == 1) {
                    float xs = val * scale;
                    float r = (gcm <= gr) ? ((xs > 15.f) ? xs : log1pf(__expf(xs))) : 0.f;
                    ((u16*)Dp)[o] = f2b(r);
                } else if (EPI == 2) {
                    float my = val;
                    float other = __shfl_xor(my, 1);
                    u32 csn = cossin[((long long)((bz << 10) + gr)) * 512 + (gcd >> 1)];
                    float cs = b2f((u16)(csn & 0xffff)), sn = b2f((u16)(csn >> 16));
                    float res = (gcd & 1) ? (cs * my - sn * other)
                                          : (cs * my + sn * other);
                    ((u16*)Dp)[o] = f2b(res);
                } else {
                    ((float*)Dp)[o] = val + bp_[gcd];
                }
            }
        }
    }
}

// ---------------------------------------------------------------------------
// fp32 -> bf16 conversion, vectorized x4
// ---------------------------------------------------------------------------
__global__ void f2b_kern(const float* __restrict__ in, u16* __restrict__ out, int n4) {
    int i = blockIdx.x * blockDim.x + threadIdx.x;
    if (i >= n4) return;
    float4 f = ((const float4*)in)[i];
    uint2 o;
    o.x = (u32)f2b(f.x) | ((u32)f2b(f.y) << 16);
    o.y = (u32)f2b(f.z) | ((u32)f2b(f.w) << 16);
    ((uint2*)out)[i] = o;
}

// 4 weight matrices in one launch (blockIdx.y selects)
__global__ void f2b_w4(const float* __restrict__ a, const float* __restrict__ b,
                       const float* __restrict__ c, const float* __restrict__ d,
                       u16* __restrict__ oa, u16* __restrict__ ob,
                       u16* __restrict__ oc, u16* __restrict__ od, int n4) {
    int i = blockIdx.x * blockDim.x + threadIdx.x;
    if (i >= n4) return;
    const float* src = (blockIdx.y == 0) ? a : (blockIdx.y == 1) ? b
                     : (blockIdx.y == 2) ? c : d;
    u16* dst = (blockIdx.y == 0) ? oa : (blockIdx.y == 1) ? ob
             : (blockIdx.y == 2) ? oc : od;
    float4 f = ((const float4*)src)[i];
    uint2 o;
    o.x = (u32)f2b(f.x) | ((u32)f2b(f.y) << 16);
    o.y = (u32)f2b(f.z) | ((u32)f2b(f.w) << 16);
    ((uint2*)dst)[i] = o;
}

// ---------------------------------------------------------------------------
// Angle suffix-sum (angle[t] = sum_{s>=t} emb[idx[s]]) in 3 phases; phase 3
// emits packed bf16 {cos, sin}.
// ---------------------------------------------------------------------------
#define TT 1024
#define CC2 512
#define NCH 32
#define CL 32

__global__ void angle_partial(const int* __restrict__ idx, const float* __restrict__ emb,
                              float* __restrict__ partial) {
    int b = blockIdx.x >> 5, ch = blockIdx.x & 31;
    int c = threadIdx.x;               // 0..511
    float s = 0.f;
    int tb = ch * CL;
    for (int t = 0; t < CL; t++) {
        int row = idx[b * TT + tb + t];
        s += emb[(long long)row * CC2 + c];
    }
    partial[((long long)b * NCH + ch) * CC2 + c] = s;
}

__global__ void angle_scan(float* __restrict__ partial) {
    int b = blockIdx.x, c = threadIdx.x;
    float run = 0.f;
    for (int ch = NCH - 1; ch >= 0; ch--) {
        long long o = ((long long)b * NCH + ch) * CC2 + c;
        float p = partial[o];
        partial[o] = run;              // exclusive suffix (chunks after this one)
        run += p;
    }
}

__global__ void angle_final(const int* __restrict__ idx, const float* __restrict__ emb,
                            const float* __restrict__ partial,
                            u32* __restrict__ cossin) {
    int b = blockIdx.x >> 5, ch = blockIdx.x & 31;
    int c = threadIdx.x;
    float run = partial[((long long)b * NCH + ch) * CC2 + c];
    for (int t = CL - 1; t >= 0; t--) {
        int tt = ch * CL + t;
        int row = idx[b * TT + tt];
        run += emb[(long long)row * CC2 + c];
        float sn, cs;
        __sincosf(run, &sn, &cs);
        cossin[((long long)b * TT + tt) * CC2 + c] = (u32)f2b(cs) | ((u32)f2b(sn) << 16);
    }
}

// ---------------------------------------------------------------------------
extern "C" void kernel_launch(void* const* d_in, const int* in_sizes, int n_in,
                              void* d_out, int out_size, void* d_ws, size_t ws_size,
                              hipStream_t stream) {
    const int Bn = 16, T = 1024, C = 1024;
    const long long TC = (long long)T * C;
    const size_t nx = (size_t)Bn * T * C;          // 16,777,216
    const size_t npairs = nx / 2;                  // 8,388,608

    const float* x   = (const float*)d_in[0];
    const int*   idx = (const int*)d_in[1];
    const float* Wk  = (const float*)d_in[2];
    const float* bk  = (const float*)d_in[3];
    const float* Wq  = (const float*)d_in[4];
    const float* bq  = (const float*)d_in[5];
    const float* Wv  = (const float*)d_in[6];
    const float* bv  = (const float*)d_in[7];
    const float* Wp  = (const float*)d_in[8];
    const float* bp  = (const float*)d_in[9];
    const float* emb = (const float*)d_in[10];
    float* out = (float*)d_out;

    // workspace (~171 MB)
    u16* xb  = (u16*)d_ws;          // x bf16; aliased as wei after QKV
    u16* kb  = xb + nx;             // k (rotated by QKV epilogue)
    u16* qb  = kb + nx;             // q (rotated); y after GEMM-O
    u16* vT  = qb + nx;             // v rotated+transposed [B][C][T]
    u32* cossin = (u32*)(vT + nx);  // [B][T][512] packed bf16 {cos,sin}
    u16* Wall = (u16*)(cossin + npairs);           // [3072][1024] = Wk|Wq|Wv
    u16* Wpb  = Wall + (size_t)3 * C * C;
    float* partial = (float*)(Wpb + (size_t)C * C);  // [B][32][512]
    u16* wei = xb;                  // alias (x dead after QKV)

    // 1) conversions to bf16
    f2b_kern<<<(int)(nx / 4 / 256), 256, 0, stream>>>(x, xb, (int)(nx / 4));
    f2b_w4<<<dim3(C * C / 4 / 256, 4), 256, 0, stream>>>(
        Wk, Wq, Wv, Wp, Wall, Wall + (size_t)C * C, Wall + (size_t)2 * C * C, Wpb,
        C * C / 4);

    // 2) angle suffix-sum -> packed cos/sin
    angle_partial<<<Bn * NCH, 512, 0, stream>>>(idx, emb, partial);
    angle_scan<<<Bn, 512, 0, stream>>>(partial);
    angle_final<<<Bn * NCH, 512, 0, stream>>>(idx, emb, partial, cossin);

    // 3) fused QKV projection: M=16384, N=3072, K=1024; bias+rotate fused,
    //    v stored transposed. XCD-swizzled by row tile (WB=24).
    gemm_nt<0, false, false, 0, true><<<3072, 256, 0, stream>>>(
        xb, 0, Wall, 0, kb, qb, vT, 0, bk, bq, bv, cossin,
        Bn * T, 3 * C, C, 1.f, 24);

    // 4) wei = softplus(k @ q^T / 32), causal-masked; batch-grouped swizzle
    gemm_nt<1, true, false, 1, false><<<1024, 256, 0, stream>>>(
        kb, TC, qb, TC, wei, nullptr, nullptr, (long long)T * T,
        nullptr, nullptr, nullptr, nullptr, T, T, C, 0.03125f, 64);

    // 5) attn = wei @ v with inverse-rotation epilogue -> y (qb);
    //    K truncated at causal boundary
    gemm_nt<2, false, true, 1, false><<<1024, 256, 0, stream>>>(
        wei, (long long)T * T, vT, (long long)C * T, qb, nullptr, nullptr, TC,
        nullptr, nullptr, nullptr, cossin, T, C, T, 1.f, 64);

    // 6) final projection -> f32 out; row-tile swizzle (WB=8)
    gemm_nt<3, false, false, 0, false><<<1024, 256, 0, stream>>>(
        qb, 0, Wpb, 0, out, nullptr, nullptr, 0, bp, nullptr, nullptr, nullptr,
        Bn * T, C, C, 1.f, 8);
}